// Round 4
// baseline (262.825 us; speedup 1.0000x reference)
//
#include <hip/hip_runtime.h>
#include <hip/hip_bf16.h>

// Problem: B=8, S=1024, D=256, H=8, HD=32
// Pipeline (3 kernels):
//   prep:      q,Wq,Wk,Wv,Wo f32 -> bf16; kv_mask (int32/bool auto) -> additive f32
//   qkv_gemm:  z=0: qh=q@Wq^T+bq, z=1: kh=q@Wk^T+bk, z=2: vt=Wv@q^T+bv (transposed V)
//   attn:      flash attention per (b, 16-row q-tile), wave=head. NO barriers in the
//              k-loop: bias read per-lane from global (L1 serves 8-way h reuse),
//              bias/K/V double-buffered in registers. Fused LN + @Wo^T+bo -> d_out.
//
// Workspace layout:
//   0        q_bf   (4 MiB)
//   4  MiB   qh     (4 MiB)
//   8  MiB   kh     (4 MiB)
//   12 MiB   vt     (4 MiB)   [256 ch][8192 seq]
//   16 MiB   w_bf   (512 KiB: Wq,Wk,Wv,Wo each 65536 bf16)
//   17 MiB   mskf   (32 KiB f32)

static constexpr int SEQ = 1024;
static constexpr float SCL  = 0.17677669529663687f;  // 1/sqrt(32)
static constexpr float NEGV = -1000000000.0f;

typedef __attribute__((ext_vector_type(8))) __bf16 bf8v;
typedef __attribute__((ext_vector_type(4))) float  f4v;

__device__ __forceinline__ f4v mfma16(bf8v a, bf8v b, f4v c) {
  return __builtin_amdgcn_mfma_f32_16x16x32_bf16(a, b, c, 0, 0, 0);
}
__device__ __forceinline__ unsigned short bfbits(float f) {
  __hip_bfloat16 hbf = __float2bfloat16(f);
  unsigned short u; __builtin_memcpy(&u, &hbf, 2); return u;
}

// ---------------------------------------------------------------- prep
__global__ __launch_bounds__(256) void prep_kernel(
    const float* __restrict__ q, const float* __restrict__ Wq,
    const float* __restrict__ Wk, const float* __restrict__ Wv,
    const float* __restrict__ Wo, const int* __restrict__ km,
    __hip_bfloat16* __restrict__ q_bf, __hip_bfloat16* __restrict__ w_bf,
    float* __restrict__ mskf)
{
  const int NQ4 = (8192 * 256) / 4;   // 524288 float4 groups for q
  const int NW4 = 65536 / 4;          // 16384 per weight
  int t = threadIdx.x;

  if (blockIdx.x == 2304) {
    __shared__ int isbool;
    if (t == 0) isbool = 0;
    __syncthreads();
    const unsigned* u = (const unsigned*)km;
    int any = 0;
    for (int i = t; i < 2048; i += 256)
      if (u[i] & ~1u) any = 1;
    if (any) isbool = 1;   // benign race
    __syncthreads();
    const unsigned char* b8 = (const unsigned char*)km;
    for (int i = t; i < 8192; i += 256) {
      int mv = isbool ? (int)b8[i] : km[i];
      mskf[i] = mv ? 0.f : NEGV;
    }
    return;
  }

  int i = blockIdx.x * 256 + t;       // < 589824 = NQ4 + 4*NW4 exactly
  const float4* src; __hip_bfloat16* dst;
  if (i < NQ4) {
    src = (const float4*)q + i;
    dst = q_bf + (long)i * 4;
  } else {
    int j = i - NQ4; int w = j >> 14; int o4 = j & (NW4 - 1);
    const float* sp = (w == 0) ? Wq : (w == 1) ? Wk : (w == 2) ? Wv : Wo;
    src = (const float4*)sp + o4;
    dst = w_bf + w * 65536 + o4 * 4;
  }
  float4 v = *src;
  ushort4 pk;
  pk.x = bfbits(v.x); pk.y = bfbits(v.y); pk.z = bfbits(v.z); pk.w = bfbits(v.w);
  *reinterpret_cast<ushort4*>(dst) = pk;
}

// ------------------------------------------------- fused QKV GEMM (K=256)
__global__ __launch_bounds__(256) void qkv_gemm(
    const __hip_bfloat16* __restrict__ q_bf, const __hip_bfloat16* __restrict__ w_bf,
    const float* __restrict__ bq, const float* __restrict__ bk,
    const float* __restrict__ bv,
    __hip_bfloat16* __restrict__ qh, __hip_bfloat16* __restrict__ kh,
    __hip_bfloat16* __restrict__ vt)
{
  int z = blockIdx.z;
  int w = threadIdx.x >> 6;
  int l = threadIdx.x & 63, lr = l & 15, lg = l >> 4;

  const __hip_bfloat16 *A, *Bm; const float* bias; __hip_bfloat16* out;
  long ldOut; int m0, n0;
  if (z < 2) {
    A = q_bf; Bm = w_bf + z * 65536; bias = z ? bk : bq; out = z ? kh : qh;
    ldOut = 256;
    m0 = blockIdx.x * 64; n0 = blockIdx.y * 128 + w * 32;
  } else {
    A = w_bf + 2 * 65536; Bm = q_bf; bias = bv; out = vt; ldOut = 8192;
    int bid = blockIdx.y * 128 + blockIdx.x;      // 0..255
    m0 = (bid >> 6) * 64; n0 = (bid & 63) * 128 + w * 32;
  }

  f4v acc[4][2];
#pragma unroll
  for (int mt = 0; mt < 4; ++mt)
#pragma unroll
    for (int nt = 0; nt < 2; ++nt) acc[mt][nt] = f4v{0.f, 0.f, 0.f, 0.f};

  const __hip_bfloat16* Ab = A  + (long)(m0 + lr) * 256 + lg * 8;
  const __hip_bfloat16* Bb = Bm + (long)(n0 + lr) * 256 + lg * 8;
#pragma unroll
  for (int k0 = 0; k0 < 256; k0 += 32) {
    bf8v af[4], bfr[2];
#pragma unroll
    for (int mt = 0; mt < 4; ++mt)
      af[mt] = *reinterpret_cast<const bf8v*>(Ab + (long)mt * 16 * 256 + k0);
#pragma unroll
    for (int nt = 0; nt < 2; ++nt)
      bfr[nt] = *reinterpret_cast<const bf8v*>(Bb + (long)nt * 16 * 256 + k0);
#pragma unroll
    for (int mt = 0; mt < 4; ++mt)
#pragma unroll
      for (int nt = 0; nt < 2; ++nt)
        acc[mt][nt] = mfma16(af[mt], bfr[nt], acc[mt][nt]);
  }

#pragma unroll
  for (int mt = 0; mt < 4; ++mt) {
    int mrow = m0 + mt * 16 + lg * 4;
#pragma unroll
    for (int nt = 0; nt < 2; ++nt) {
      int ncol = n0 + nt * 16 + lr;
#pragma unroll
      for (int r = 0; r < 4; ++r) {
        float v = acc[mt][nt][r] + ((z == 2) ? bias[mrow + r] : bias[ncol]);
        out[(long)(mrow + r) * ldOut + ncol] = __float2bfloat16(v);
      }
    }
  }
}

// ---------------------------------------------------------------- attention
// grid = 512 (b*64 + qtile), block = 512 (8 waves; wave = head). QT=16, KT=32.
// No barriers in the k-loop. Fused LayerNorm + out-projection epilogue.
__global__ __launch_bounds__(512, 4) void attn_kernel(
    const __hip_bfloat16* __restrict__ qh, const __hip_bfloat16* __restrict__ kh,
    const __hip_bfloat16* __restrict__ vt, const float* __restrict__ bias,
    const float* __restrict__ mskf, const __hip_bfloat16* __restrict__ wob,
    const float* __restrict__ gamma, const float* __restrict__ beta,
    const float* __restrict__ bo, float* __restrict__ outp)
{
  __shared__ float msmall[1024];                           // additive mask, whole row
  __shared__ __align__(16) __hip_bfloat16 psm[8][16 * 40]; // per-wave P
  __shared__ float osm[16 * 261];                          // attn out f32 [q][d]
  __shared__ __align__(16) __hip_bfloat16 ansm[16 * 264];  // LN out bf16 [q][d]

  int bb = blockIdx.x >> 6;
  int qt = blockIdx.x & 63;
  int h  = threadIdx.x >> 6;
  int l  = threadIdx.x & 63, lr = l & 15, lg = l >> 4;
  int q0 = qt * 16;
  long bS = (long)bb * SEQ;
  int t = threadIdx.x;

  // mask preload (one-time barrier)
  for (int i = t; i < 1024; i += 512) msmall[i] = mskf[bS + i];
  __syncthreads();

  bf8v qf = *reinterpret_cast<const bf8v*>(qh + (bS + q0 + lr) * 256 + h * 32 + lg * 8);

  f4v o[2];
  float mrun[4], lrun[4];
#pragma unroll
  for (int nt = 0; nt < 2; ++nt) o[nt] = f4v{0.f, 0.f, 0.f, 0.f};
#pragma unroll
  for (int r = 0; r < 4; ++r) { mrun[r] = -1e30f; lrun[r] = 0.f; }

  // per-lane bias base (f32 index): (bS+q0+lg*4)*8192 + h + lr*8
  const float* bbase = bias + (bS + q0 + lg * 4) * 8192L + h + lr * 8;

  auto issueB = [&](int kbase, float (&dst)[8]) {
#pragma unroll
    for (int r = 0; r < 4; ++r) {
      const float* p = bbase + (long)r * 8192 + kbase * 8;
      dst[2 * r]     = p[0];
      dst[2 * r + 1] = p[128];
    }
  };
  auto issueKV = [&](int kbase, bf8v (&kf)[2], bf8v (&vf)[2]) {
#pragma unroll
    for (int nt = 0; nt < 2; ++nt)
      kf[nt] = *reinterpret_cast<const bf8v*>(
          kh + (bS + kbase + nt * 16 + lr) * 256 + h * 32 + lg * 8);
#pragma unroll
    for (int n2 = 0; n2 < 2; ++n2)
      vf[n2] = *reinterpret_cast<const bf8v*>(
          vt + (long)(h * 32 + n2 * 16 + lr) * 8192 + bS + kbase + lg * 8);
  };

  float brA[8], brB[8];
  bf8v kfA[2], kfB[2], vfA[2], vfB[2];

  auto body = [&](int kt, float (&brC)[8], float (&brN)[8],
                  bf8v (&kfC)[2], bf8v (&kfN)[2],
                  bf8v (&vfC)[2], bf8v (&vfN)[2]) {
    int kbase = kt * 32;
    if (kt + 1 < 32) { issueB(kbase + 32, brN); issueKV(kbase + 32, kfN, vfN); }
    float msk0 = msmall[kbase + lr];
    float msk1 = msmall[kbase + 16 + lr];

    f4v s0 = mfma16(qf, kfC[0], f4v{0.f, 0.f, 0.f, 0.f});
    f4v s1 = mfma16(qf, kfC[1], f4v{0.f, 0.f, 0.f, 0.f});

#pragma unroll
    for (int r = 0; r < 4; ++r) {
      int qq = lg * 4 + r;
      float v0 = s0[r] * SCL + brC[2 * r]     + msk0;
      float v1 = s1[r] * SCL + brC[2 * r + 1] + msk1;
      float tm = fmaxf(v0, v1);
#pragma unroll
      for (int mm = 1; mm < 16; mm <<= 1) tm = fmaxf(tm, __shfl_xor(tm, mm));
      float mo = mrun[r], mn = fmaxf(mo, tm);
      float al = __expf(mo - mn);
      float p0 = __expf(v0 - mn), p1 = __expf(v1 - mn);
      float ts = p0 + p1;
#pragma unroll
      for (int mm = 1; mm < 16; mm <<= 1) ts += __shfl_xor(ts, mm);
      mrun[r] = mn;
      lrun[r] = lrun[r] * al + ts;
      o[0][r] *= al; o[1][r] *= al;
      psm[h][qq * 40 + lr]      = __float2bfloat16(p0);
      psm[h][qq * 40 + 16 + lr] = __float2bfloat16(p1);
    }

    bf8v pa = *reinterpret_cast<const bf8v*>(&psm[h][lr * 40 + lg * 8]);
    o[0] = mfma16(pa, vfC[0], o[0]);
    o[1] = mfma16(pa, vfC[1], o[1]);
  };

  issueB(0, brA); issueKV(0, kfA, vfA);
  for (int kt2 = 0; kt2 < 16; ++kt2) {
    body(2 * kt2,     brA, brB, kfA, kfB, vfA, vfB);
    body(2 * kt2 + 1, brB, brA, kfB, kfA, vfB, vfA);
  }

  // ---- epilogue: stage normalized attn-out, LayerNorm, out-projection ----
  __syncthreads();
#pragma unroll
  for (int r = 0; r < 4; ++r) {
    float inv = 1.f / lrun[r];
    int qq = lg * 4 + r;
    osm[qq * 261 + h * 32 + lr]      = o[0][r] * inv;
    osm[qq * 261 + h * 32 + 16 + lr] = o[1][r] * inv;
  }
  __syncthreads();

  {
    int row = t >> 5;
    int c8 = (t & 31) * 8;
    float vv[8]; float sm = 0.f, sq = 0.f;
#pragma unroll
    for (int j = 0; j < 8; ++j) {
      vv[j] = osm[row * 261 + c8 + j];
      sm += vv[j]; sq += vv[j] * vv[j];
    }
#pragma unroll
    for (int mm = 1; mm < 32; mm <<= 1) { sm += __shfl_xor(sm, mm); sq += __shfl_xor(sq, mm); }
    float mean = sm * (1.f / 256.f);
    float var  = sq * (1.f / 256.f) - mean * mean;
    float rstd = rsqrtf(var + 1e-5f);
    float4 g0 = *reinterpret_cast<const float4*>(gamma + c8);
    float4 g1 = *reinterpret_cast<const float4*>(gamma + c8 + 4);
    float4 b0 = *reinterpret_cast<const float4*>(beta + c8);
    float4 b1 = *reinterpret_cast<const float4*>(beta + c8 + 4);
    float gg[8] = {g0.x, g0.y, g0.z, g0.w, g1.x, g1.y, g1.z, g1.w};
    float bb8[8] = {b0.x, b0.y, b0.z, b0.w, b1.x, b1.y, b1.z, b1.w};
    ushort4 pkA, pkB;
    pkA.x = bfbits((vv[0] - mean) * rstd * gg[0] + bb8[0]);
    pkA.y = bfbits((vv[1] - mean) * rstd * gg[1] + bb8[1]);
    pkA.z = bfbits((vv[2] - mean) * rstd * gg[2] + bb8[2]);
    pkA.w = bfbits((vv[3] - mean) * rstd * gg[3] + bb8[3]);
    pkB.x = bfbits((vv[4] - mean) * rstd * gg[4] + bb8[4]);
    pkB.y = bfbits((vv[5] - mean) * rstd * gg[5] + bb8[5]);
    pkB.z = bfbits((vv[6] - mean) * rstd * gg[6] + bb8[6]);
    pkB.w = bfbits((vv[7] - mean) * rstd * gg[7] + bb8[7]);
    *reinterpret_cast<ushort4*>(&ansm[row * 264 + c8])     = pkA;
    *reinterpret_cast<ushort4*>(&ansm[row * 264 + c8 + 4]) = pkB;
  }
  __syncthreads();

  // out-projection: 16x256 @ Wo^T(256x256), wave h covers cols h*32..h*32+31
  f4v acc2[2];
  acc2[0] = f4v{0.f, 0.f, 0.f, 0.f}; acc2[1] = f4v{0.f, 0.f, 0.f, 0.f};
#pragma unroll
  for (int k0 = 0; k0 < 256; k0 += 32) {
    bf8v afr = *reinterpret_cast<const bf8v*>(&ansm[lr * 264 + lg * 8 + k0]);
#pragma unroll
    for (int nt = 0; nt < 2; ++nt) {
      bf8v bfrg = *reinterpret_cast<const bf8v*>(
          wob + (long)(h * 32 + nt * 16 + lr) * 256 + lg * 8 + k0);
      acc2[nt] = mfma16(afr, bfrg, acc2[nt]);
    }
  }
#pragma unroll
  for (int nt = 0; nt < 2; ++nt) {
    int ocol = h * 32 + nt * 16 + lr;
    float bov = bo[ocol];
#pragma unroll
    for (int r = 0; r < 4; ++r) {
      int orow = q0 + lg * 4 + r;
      outp[(bS + orow) * 256 + ocol] = acc2[nt][r] + bov;
    }
  }
}

// ---------------------------------------------------------------- launch
extern "C" void kernel_launch(void* const* d_in, const int* in_sizes, int n_in,
                              void* d_out, int out_size, void* d_ws, size_t ws_size,
                              hipStream_t stream) {
  const float* q   = (const float*)d_in[0];
  const int*   km  = (const int*)d_in[1];
  const float* bias = (const float*)d_in[2];
  const float* Wq = (const float*)d_in[3];
  const float* bq = (const float*)d_in[4];
  const float* Wk = (const float*)d_in[5];
  const float* bk = (const float*)d_in[6];
  const float* Wv = (const float*)d_in[7];
  const float* bv = (const float*)d_in[8];
  const float* gamma = (const float*)d_in[9];
  const float* beta  = (const float*)d_in[10];
  const float* Wo = (const float*)d_in[11];
  const float* bo = (const float*)d_in[12];

  char* wsb = (char*)d_ws;
  __hip_bfloat16* q_bf = (__hip_bfloat16*)(wsb + 0);
  __hip_bfloat16* qh   = (__hip_bfloat16*)(wsb + (4  << 20));
  __hip_bfloat16* kh   = (__hip_bfloat16*)(wsb + (8  << 20));
  __hip_bfloat16* vt   = (__hip_bfloat16*)(wsb + (12 << 20));
  __hip_bfloat16* wbf  = (__hip_bfloat16*)(wsb + (16 << 20));
  float*          mskf = (float*)         (wsb + (17 << 20));
  __hip_bfloat16* wob  = wbf + 196608;

  prep_kernel<<<2305, 256, 0, stream>>>(q, Wq, Wk, Wv, Wo, km, q_bf, wbf, mskf);
  qkv_gemm<<<dim3(128, 2, 3), 256, 0, stream>>>(q_bf, wbf, bq, bk, bv, qh, kh, vt);
  attn_kernel<<<512, 512, 0, stream>>>(qh, kh, vt, bias, mskf, wob,
                                       gamma, beta, bo, (float*)d_out);
}

// Round 5
// 138.737 us; speedup vs baseline: 1.8944x; 1.8944x over previous
//
#include <hip/hip_runtime.h>
#include <hip/hip_bf16.h>

// Problem: B=8, S=1024, D=256, H=8, HD=32
// Pipeline (3 kernels):
//   prep:      q,Wq,Wk,Wv,Wo f32 -> bf16; kv_mask (int32/bool auto) -> additive f32
//   qkv_gemm:  z=0: qh=q@Wq^T+bq, z=1: kh=q@Wk^T+bk, z=2: vt=Wv@q^T+bv (transposed V)
//   attn:      flash attention per (b, 16-row q-tile), wave=head.
//              Coalesced bias staging, LDS double-buffer, ONE barrier per k-tile.
//              Swapped QK^T (mfma(K,Q)) -> q lane-local softmax (2 shfl reduce).
//              Fused LayerNorm + out-projection (@Wo^T+bo) -> d_out (f32).
//
// Workspace: q_bf(4M) qh(4M@4M) kh(4M@8M) vt(4M@12M) w_bf(512K@16M) mskf(32K@17M)

static constexpr int SEQ = 1024;
static constexpr float SCL  = 0.17677669529663687f;  // 1/sqrt(32)
static constexpr float NEGV = -1000000000.0f;

typedef __attribute__((ext_vector_type(8))) __bf16 bf8v;
typedef __attribute__((ext_vector_type(4))) float  f4v;

__device__ __forceinline__ f4v mfma16(bf8v a, bf8v b, f4v c) {
  return __builtin_amdgcn_mfma_f32_16x16x32_bf16(a, b, c, 0, 0, 0);
}
__device__ __forceinline__ unsigned short bfbits(float f) {
  __hip_bfloat16 hbf = __float2bfloat16(f);
  unsigned short u; __builtin_memcpy(&u, &hbf, 2); return u;
}

// ---------------------------------------------------------------- prep
__global__ __launch_bounds__(256) void prep_kernel(
    const float* __restrict__ q, const float* __restrict__ Wq,
    const float* __restrict__ Wk, const float* __restrict__ Wv,
    const float* __restrict__ Wo, const int* __restrict__ km,
    __hip_bfloat16* __restrict__ q_bf, __hip_bfloat16* __restrict__ w_bf,
    float* __restrict__ mskf)
{
  const int NQ4 = (8192 * 256) / 4;   // 524288 float4 groups for q
  const int NW4 = 65536 / 4;          // 16384 per weight
  int t = threadIdx.x;

  if (blockIdx.x == 2304) {
    __shared__ int isbool;
    if (t == 0) isbool = 0;
    __syncthreads();
    const unsigned* u = (const unsigned*)km;
    int any = 0;
    for (int i = t; i < 2048; i += 256)
      if (u[i] & ~1u) any = 1;
    if (any) isbool = 1;   // benign race
    __syncthreads();
    const unsigned char* b8 = (const unsigned char*)km;
    for (int i = t; i < 8192; i += 256) {
      int mv = isbool ? (int)b8[i] : km[i];
      mskf[i] = mv ? 0.f : NEGV;
    }
    return;
  }

  int i = blockIdx.x * 256 + t;       // < 589824 = NQ4 + 4*NW4 exactly
  const float4* src; __hip_bfloat16* dst;
  if (i < NQ4) {
    src = (const float4*)q + i;
    dst = q_bf + (long)i * 4;
  } else {
    int j = i - NQ4; int w = j >> 14; int o4 = j & (NW4 - 1);
    const float* sp = (w == 0) ? Wq : (w == 1) ? Wk : (w == 2) ? Wv : Wo;
    src = (const float4*)sp + o4;
    dst = w_bf + w * 65536 + o4 * 4;
  }
  float4 v = *src;
  ushort4 pk;
  pk.x = bfbits(v.x); pk.y = bfbits(v.y); pk.z = bfbits(v.z); pk.w = bfbits(v.w);
  *reinterpret_cast<ushort4*>(dst) = pk;
}

// ------------------------------------------------- fused QKV GEMM (K=256)
__global__ __launch_bounds__(256) void qkv_gemm(
    const __hip_bfloat16* __restrict__ q_bf, const __hip_bfloat16* __restrict__ w_bf,
    const float* __restrict__ bq, const float* __restrict__ bk,
    const float* __restrict__ bv,
    __hip_bfloat16* __restrict__ qh, __hip_bfloat16* __restrict__ kh,
    __hip_bfloat16* __restrict__ vt)
{
  int z = blockIdx.z;
  int w = threadIdx.x >> 6;
  int l = threadIdx.x & 63, lr = l & 15, lg = l >> 4;

  const __hip_bfloat16 *A, *Bm; const float* bias; __hip_bfloat16* out;
  long ldOut; int m0, n0;
  if (z < 2) {
    A = q_bf; Bm = w_bf + z * 65536; bias = z ? bk : bq; out = z ? kh : qh;
    ldOut = 256;
    m0 = blockIdx.x * 64; n0 = blockIdx.y * 128 + w * 32;
  } else {
    A = w_bf + 2 * 65536; Bm = q_bf; bias = bv; out = vt; ldOut = 8192;
    int bid = blockIdx.y * 128 + blockIdx.x;      // 0..255
    m0 = (bid >> 6) * 64; n0 = (bid & 63) * 128 + w * 32;
  }

  f4v acc[4][2];
#pragma unroll
  for (int mt = 0; mt < 4; ++mt)
#pragma unroll
    for (int nt = 0; nt < 2; ++nt) acc[mt][nt] = f4v{0.f, 0.f, 0.f, 0.f};

  const __hip_bfloat16* Ab = A  + (long)(m0 + lr) * 256 + lg * 8;
  const __hip_bfloat16* Bb = Bm + (long)(n0 + lr) * 256 + lg * 8;
#pragma unroll
  for (int k0 = 0; k0 < 256; k0 += 32) {
    bf8v af[4], bfr[2];
#pragma unroll
    for (int mt = 0; mt < 4; ++mt)
      af[mt] = *reinterpret_cast<const bf8v*>(Ab + (long)mt * 16 * 256 + k0);
#pragma unroll
    for (int nt = 0; nt < 2; ++nt)
      bfr[nt] = *reinterpret_cast<const bf8v*>(Bb + (long)nt * 16 * 256 + k0);
#pragma unroll
    for (int mt = 0; mt < 4; ++mt)
#pragma unroll
      for (int nt = 0; nt < 2; ++nt)
        acc[mt][nt] = mfma16(af[mt], bfr[nt], acc[mt][nt]);
  }

#pragma unroll
  for (int mt = 0; mt < 4; ++mt) {
    int mrow = m0 + mt * 16 + lg * 4;
#pragma unroll
    for (int nt = 0; nt < 2; ++nt) {
      int ncol = n0 + nt * 16 + lr;
#pragma unroll
      for (int r = 0; r < 4; ++r) {
        float v = acc[mt][nt][r] + ((z == 2) ? bias[mrow + r] : bias[ncol]);
        out[(long)(mrow + r) * ldOut + ncol] = __float2bfloat16(v);
      }
    }
  }
}

// ---------------------------------------------------------------- attention
// grid = 512 (b*64 + qtile), block = 512 (8 waves; wave = head). QT=16, KT=32.
// One barrier per k-tile; bias double-buffered in LDS; swapped QK^T softmax.
__global__ __launch_bounds__(512) void attn_kernel(
    const __hip_bfloat16* __restrict__ qh, const __hip_bfloat16* __restrict__ kh,
    const __hip_bfloat16* __restrict__ vt, const float* __restrict__ bias,
    const float* __restrict__ mskf, const __hip_bfloat16* __restrict__ wob,
    const float* __restrict__ gamma, const float* __restrict__ beta,
    const float* __restrict__ bo, float* __restrict__ outp)
{
  // LDS union: loop phase: bsm[2][16*267] f32 (34176 B) | msk[1024] f32 (4096 B)
  //            | psm[8][16*40] bf16 (10240 B)  => 48512 B
  // epilogue:  osm[16*261] f32 (16704 B) + ansm[16*264] bf16 (8448 B) alias bsm.
  __shared__ __align__(16) char smem[48512];
  float* bsm = (float*)smem;
  float* msk = (float*)(smem + 34176);
  __hip_bfloat16* psm = (__hip_bfloat16*)(smem + 38272);
  float* osm = (float*)smem;
  __hip_bfloat16* ansm = (__hip_bfloat16*)(smem + 16704);

  int bb = blockIdx.x >> 6;
  int qt = blockIdx.x & 63;
  int h  = threadIdx.x >> 6;
  int l  = threadIdx.x & 63, lr = l & 15, lg = l >> 4;
  int q0 = qt * 16;
  long bS = (long)bb * SEQ;
  int t = threadIdx.x;

  // mask preload (covered by the prologue barrier)
  for (int i = t; i < 1024; i += 512) msk[i] = mskf[bS + i];

  bf8v qf = *reinterpret_cast<const bf8v*>(qh + (bS + q0 + lr) * 256 + h * 32 + lg * 8);

  f4v o[2];
  o[0] = f4v{0.f, 0.f, 0.f, 0.f}; o[1] = f4v{0.f, 0.f, 0.f, 0.f};
  float mrun = -1e30f, lrun = 0.f;

  const float* bgbase = bias + (bS + q0) * 8192L;
  int qq0 = t >> 6;      // wave-uniform
  int c4  = t & 63;

  auto loadBias = [&](int kbase, float4 (&br)[2]) {
#pragma unroll
    for (int r2 = 0; r2 < 2; ++r2)
      br[r2] = *reinterpret_cast<const float4*>(
          bgbase + (long)(r2 * 8 + qq0) * 8192 + kbase * 8 + c4 * 4);
  };
  auto writeBias = [&](int buf, const float4 (&br)[2]) {
    float* bp = bsm + buf * (16 * 267);
    int kk = c4 >> 1, h0 = (c4 & 1) * 4;
#pragma unroll
    for (int r2 = 0; r2 < 2; ++r2) {
      int qq = r2 * 8 + qq0;
      float vv[4] = {br[r2].x, br[r2].y, br[r2].z, br[r2].w};
#pragma unroll
      for (int ii = 0; ii < 4; ++ii)
        bp[qq * 267 + (h0 + ii) * 33 + kk] = vv[ii];
    }
  };
  auto issueKV = [&](int kbase, bf8v (&kf)[2], bf8v (&vf)[2]) {
#pragma unroll
    for (int nt = 0; nt < 2; ++nt)
      kf[nt] = *reinterpret_cast<const bf8v*>(
          kh + (bS + kbase + nt * 16 + lr) * 256 + h * 32 + lg * 8);
#pragma unroll
    for (int n2 = 0; n2 < 2; ++n2)
      vf[n2] = *reinterpret_cast<const bf8v*>(
          vt + (long)(h * 32 + n2 * 16 + lr) * 8192 + bS + kbase + lg * 8);
  };

  float4 brA[2], brB[2];
  bf8v kfA[2], kfB[2], vfA[2], vfB[2];

  // body: computes tile kt from bsm[kt&1]/kfC/vfC, loads tile kt+1 into brN/kfN/vfN,
  // writes bias tile kt+1 into bsm[(kt+1)&1], ends with ONE barrier.
  auto body = [&](int kt, float4 (&brN)[2],
                  bf8v (&kfC)[2], bf8v (&kfN)[2],
                  bf8v (&vfC)[2], bf8v (&vfN)[2]) {
    int kbase = kt * 32;
    bool more = (kt + 1 < 32);
    if (more) { loadBias(kbase + 32, brN); issueKV(kbase + 32, kfN, vfN); }

    const float* bp = bsm + (kt & 1) * (16 * 267) + lr * 267 + h * 33;

    // swapped QK^T: col = q (lane&15), row = k_local (lg*4+r)
    f4v zero = f4v{0.f, 0.f, 0.f, 0.f};
    f4v s0 = mfma16(kfC[0], qf, zero);
    f4v s1 = mfma16(kfC[1], qf, zero);

    float v[8];
#pragma unroll
    for (int j = 0; j < 4; ++j) {
      int k0i = lg * 4 + j;
      v[j]     = s0[j] * SCL + bp[k0i]      + msk[kbase + k0i];
      v[4 + j] = s1[j] * SCL + bp[16 + k0i] + msk[kbase + 16 + k0i];
    }
    float tm = fmaxf(fmaxf(fmaxf(v[0], v[1]), fmaxf(v[2], v[3])),
                     fmaxf(fmaxf(v[4], v[5]), fmaxf(v[6], v[7])));
    tm = fmaxf(tm, __shfl_xor(tm, 16));
    tm = fmaxf(tm, __shfl_xor(tm, 32));
    float mn = fmaxf(mrun, tm);
    float al = __expf(mrun - mn);
    mrun = mn;
    float p[8]; float ts = 0.f;
#pragma unroll
    for (int j = 0; j < 8; ++j) { p[j] = __expf(v[j] - mn); ts += p[j]; }
    ts += __shfl_xor(ts, 16);
    ts += __shfl_xor(ts, 32);
    lrun = lrun * al + ts;

    // P -> per-wave LDS [q=lr][k]
    __hip_bfloat16* pp = psm + h * 640 + lr * 40;
#pragma unroll
    for (int j = 0; j < 4; ++j) {
      pp[lg * 4 + j]      = __float2bfloat16(p[j]);
      pp[16 + lg * 4 + j] = __float2bfloat16(p[4 + j]);
    }

    // rescale O (its q = lg*4+r): broadcast al from lane (lg*4+r)
#pragma unroll
    for (int r = 0; r < 4; ++r) {
      float alr = __shfl(al, lg * 4 + r);
      o[0][r] *= alr; o[1][r] *= alr;
    }

    bf8v pa = *reinterpret_cast<const bf8v*>(psm + h * 640 + lr * 40 + lg * 8);
    o[0] = mfma16(pa, vfC[0], o[0]);
    o[1] = mfma16(pa, vfC[1], o[1]);

    if (more) writeBias((kt + 1) & 1, brN);   // vmcnt waits land here (late)
    __syncthreads();                          // one barrier per tile
  };

  // prologue: stage tile 0
  loadBias(0, brA); issueKV(0, kfA, vfA);
  writeBias(0, brA);
  __syncthreads();

  for (int kt2 = 0; kt2 < 16; ++kt2) {
    body(2 * kt2,     brB, kfA, kfB, vfA, vfB);
    body(2 * kt2 + 1, brA, kfB, kfA, vfB, vfA);
  }

  // ---- epilogue (last body ended with a barrier; bsm region now reusable) ----
  float rinv = 1.f / lrun;
#pragma unroll
  for (int r = 0; r < 4; ++r) {
    float invr = __shfl(rinv, lg * 4 + r);
    int qq = lg * 4 + r;
    osm[qq * 261 + h * 32 + lr]      = o[0][r] * invr;
    osm[qq * 261 + h * 32 + 16 + lr] = o[1][r] * invr;
  }
  __syncthreads();

  {
    int row = t >> 5;
    int c8 = (t & 31) * 8;
    float vv[8]; float sm = 0.f, sq = 0.f;
#pragma unroll
    for (int j = 0; j < 8; ++j) {
      vv[j] = osm[row * 261 + c8 + j];
      sm += vv[j]; sq += vv[j] * vv[j];
    }
#pragma unroll
    for (int mm = 1; mm < 32; mm <<= 1) { sm += __shfl_xor(sm, mm); sq += __shfl_xor(sq, mm); }
    float mean = sm * (1.f / 256.f);
    float var  = sq * (1.f / 256.f) - mean * mean;
    float rstd = rsqrtf(var + 1e-5f);
    float4 g0 = *reinterpret_cast<const float4*>(gamma + c8);
    float4 g1 = *reinterpret_cast<const float4*>(gamma + c8 + 4);
    float4 b0 = *reinterpret_cast<const float4*>(beta + c8);
    float4 b1 = *reinterpret_cast<const float4*>(beta + c8 + 4);
    float gg[8] = {g0.x, g0.y, g0.z, g0.w, g1.x, g1.y, g1.z, g1.w};
    float bb8[8] = {b0.x, b0.y, b0.z, b0.w, b1.x, b1.y, b1.z, b1.w};
    ushort4 pkA, pkB;
    pkA.x = bfbits((vv[0] - mean) * rstd * gg[0] + bb8[0]);
    pkA.y = bfbits((vv[1] - mean) * rstd * gg[1] + bb8[1]);
    pkA.z = bfbits((vv[2] - mean) * rstd * gg[2] + bb8[2]);
    pkA.w = bfbits((vv[3] - mean) * rstd * gg[3] + bb8[3]);
    pkB.x = bfbits((vv[4] - mean) * rstd * gg[4] + bb8[4]);
    pkB.y = bfbits((vv[5] - mean) * rstd * gg[5] + bb8[5]);
    pkB.z = bfbits((vv[6] - mean) * rstd * gg[6] + bb8[6]);
    pkB.w = bfbits((vv[7] - mean) * rstd * gg[7] + bb8[7]);
    *reinterpret_cast<ushort4*>(&ansm[row * 264 + c8])     = pkA;
    *reinterpret_cast<ushort4*>(&ansm[row * 264 + c8 + 4]) = pkB;
  }
  __syncthreads();

  // out-projection: 16x256 @ Wo^T(256x256), wave h covers cols h*32..h*32+31
  f4v acc2[2];
  acc2[0] = f4v{0.f, 0.f, 0.f, 0.f}; acc2[1] = f4v{0.f, 0.f, 0.f, 0.f};
#pragma unroll
  for (int k0 = 0; k0 < 256; k0 += 32) {
    bf8v afr = *reinterpret_cast<const bf8v*>(&ansm[lr * 264 + lg * 8 + k0]);
#pragma unroll
    for (int nt = 0; nt < 2; ++nt) {
      bf8v bfrg = *reinterpret_cast<const bf8v*>(
          wob + (long)(h * 32 + nt * 16 + lr) * 256 + lg * 8 + k0);
      acc2[nt] = mfma16(afr, bfrg, acc2[nt]);
    }
  }
#pragma unroll
  for (int nt = 0; nt < 2; ++nt) {
    int ocol = h * 32 + nt * 16 + lr;
    float bov = bo[ocol];
#pragma unroll
    for (int r = 0; r < 4; ++r) {
      int orow = q0 + lg * 4 + r;
      outp[(bS + orow) * 256 + ocol] = acc2[nt][r] + bov;
    }
  }
}

// ---------------------------------------------------------------- launch
extern "C" void kernel_launch(void* const* d_in, const int* in_sizes, int n_in,
                              void* d_out, int out_size, void* d_ws, size_t ws_size,
                              hipStream_t stream) {
  const float* q   = (const float*)d_in[0];
  const int*   km  = (const int*)d_in[1];
  const float* bias = (const float*)d_in[2];
  const float* Wq = (const float*)d_in[3];
  const float* bq = (const float*)d_in[4];
  const float* Wk = (const float*)d_in[5];
  const float* bk = (const float*)d_in[6];
  const float* Wv = (const float*)d_in[7];
  const float* bv = (const float*)d_in[8];
  const float* gamma = (const float*)d_in[9];
  const float* beta  = (const float*)d_in[10];
  const float* Wo = (const float*)d_in[11];
  const float* bo = (const float*)d_in[12];

  char* wsb = (char*)d_ws;
  __hip_bfloat16* q_bf = (__hip_bfloat16*)(wsb + 0);
  __hip_bfloat16* qh   = (__hip_bfloat16*)(wsb + (4  << 20));
  __hip_bfloat16* kh   = (__hip_bfloat16*)(wsb + (8  << 20));
  __hip_bfloat16* vt   = (__hip_bfloat16*)(wsb + (12 << 20));
  __hip_bfloat16* wbf  = (__hip_bfloat16*)(wsb + (16 << 20));
  float*          mskf = (float*)         (wsb + (17 << 20));
  __hip_bfloat16* wob  = wbf + 196608;

  prep_kernel<<<2305, 256, 0, stream>>>(q, Wq, Wk, Wv, Wo, km, q_bf, wbf, mskf);
  qkv_gemm<<<dim3(128, 2, 3), 256, 0, stream>>>(q_bf, wbf, bq, bk, bv, qh, kh, vt);
  attn_kernel<<<512, 512, 0, stream>>>(qh, kh, vt, bias, mskf, wob,
                                       gamma, beta, bo, (float*)d_out);
}